// Round 8
// baseline (362.062 us; speedup 1.0000x reference)
//
#include <hip/hip_runtime.h>

// GraphConstruction: x[1,1024,1024] fp32 -> A[4096,4096] in {0,1} fp32.
// patches[n,r,k] = x[h,w], h = (n&15)*64 + (r>>2)*16 + (n>>8),
//                          w = (r&3)*256 + k*16 + ((n>>4)&15)
// LOCKED NUMERICS (R6..R20, absmax 0):
//   sq[n,k]: acc = p0^2; acc = acc + fl(p_r^2), r ascending (plain adds)
//   G: acc = fmaf(a_r, b_r, acc), r ascending;  d2 = fmaf(-2,G,fl(si+sj))
//   decision: all_k (d2 <= 49.0f) == !any_k (d2 > 49.0f) -> per-cell FAIL
//   BIT. A bit-exactly symmetric (fmaf/add commute under operand swap) ->
//   mirror stores; duplicate identical writes benign.
// R21: 64x128 tile, 4x8 per-thread, 256 threads — the largest tile whose
//   live set (~90: acc 32 + a 16 + b 4 + addr) fits the EMPIRICAL no-spill
//   co-residency regime (<=128 VGPR, no amdgpu attributes). Attribute law
//   measured R14-R20: default->84, (2,2)->128, (1,x)->200 BUT 1 wave/SIMD
//   runtime; >=129 VGPR never co-resides. So stop fighting the allocator;
//   shrink the tile to fit. Economics: 12 LDS reads / 128 fmaf = 1.5 B/FMA
//   (R13 = 2.0) -> LDS pipe ~76us vs R13's ~100us binding pipe.
//   b-reads: rows tx*8+v, tx in 0..3 per wave -> 4 addresses, 16-lane
//   broadcast each, 4 distinct bank groups (swz algebra) -> conflict-FREE
//   (R13's b-reads were 2-way on every read). a-reads 16 rows, ~2-way, free.
//   Tiling: tiles I>=2J (I<64, J<32) = 1056 blocks; straddle tiles handled
//   by per-thread active mask (R20-proven, absmax 0). Staging decoders are
//   the R13 (64-row) and R19 (128-row) proven patterns. LDS 29.2KB.

#define NPATCH 4096
#define BM 64
#define BN 128
#define NPH 8
#define KC 2
#define RSTRIDE 9          // float4 per row (8 data chunks + 1 pad)

__device__ __forceinline__ int swzrow(int row) {
    return ((row >> 2) + (row >> 5)) & 7;
}

// dot-accumulate: components x..w = r ascending (locked chain)
#define FMA4(dst, av, bv)              \
    dst = fmaf(av.x, bv.x, dst);       \
    dst = fmaf(av.y, bv.y, dst);       \
    dst = fmaf(av.z, bv.z, dst);       \
    dst = fmaf(av.w, bv.w, dst);

#define LDA(u)                                                                 \
    const float4 a##u = Si[(ty * 4 + u) * RSTRIDE +                            \
                           (c ^ swzrow(ty * 4 + u))];

// d{u}A holds cols v=0..3, d{u}B cols v=4..7
#define COL(v, comp)                                                           \
    {                                                                          \
        const int row_ = tx * 8 + v;                                           \
        const float4 b_ = Sj[row_ * RSTRIDE + (c ^ swzrow(row_))];             \
        FMA4(d0##comp, a0, b_)                                                 \
        FMA4(d1##comp, a1, b_)                                                 \
        FMA4(d2##comp, a2, b_)                                                 \
        FMA4(d3##comp, a3, b_)                                                 \
    }

#define CELL(dcomp, siv, sjv, bit)                                             \
    {                                                                          \
        const float s_ = (siv) + (sjv);           /* fl(si+sj) */              \
        const float d2_ = fmaf(-2.0f, dcomp, s_); /* fl(s-2G)  */              \
        fail |= (d2_ > 49.0f ? 1u : 0u) << (bit);                              \
    }

#define EPIROW(u, siv)                               \
    CELL(d##u##A.x, siv, sj0.x, (u) * 8 + 0)         \
    CELL(d##u##A.y, siv, sj0.y, (u) * 8 + 1)         \
    CELL(d##u##A.z, siv, sj0.z, (u) * 8 + 2)         \
    CELL(d##u##A.w, siv, sj0.w, (u) * 8 + 3)         \
    CELL(d##u##B.x, siv, sj1.x, (u) * 8 + 4)         \
    CELL(d##u##B.y, siv, sj1.y, (u) * 8 + 5)         \
    CELL(d##u##B.z, siv, sj1.z, (u) * 8 + 6)         \
    CELL(d##u##B.w, siv, sj1.w, (u) * 8 + 7)

__global__ __launch_bounds__(256, 3) void adj_kernel(const float* __restrict__ x,
                                                     float* __restrict__ A) {
#pragma clang fp contract(off)
    __shared__ float4 Si[BM * RSTRIDE];
    __shared__ float4 Sj[BN * RSTRIDE];
    __shared__ float sqi[KC][BM];
    __shared__ float sqj[KC][BN];

    // blockIdx -> tile (I rows of 64, J cols of 128), I >= 2J.
    // cum(J) = sum_{J'<J}(64-2J') = J*(65-J). 1056 total.
    int t = blockIdx.x;
    int J = (int)((65.0f - sqrtf(4225.0f - 4.0f * (float)t)) * 0.5f);
    if (J < 0) J = 0;
    while ((J + 1) * (65 - (J + 1)) <= t) ++J;
    while (J * (65 - J) > t) --J;
    const int I = 2 * J + (t - J * (65 - J));

    const int i0 = I * BM;
    const int j0 = J * BN;
    const int tid = threadIdx.x;
    const int ty = tid & 15;       // i-rows ty*4..+3   (fast index)
    const int tx = tid >> 4;       // j-cols tx*8..+7   (slow index)
    const bool active = (i0 + ty * 4 + 3) >= (j0 + tx * 8);

    unsigned fail = 0u;            // bit u*8+v, u<4, v<8

    for (int kp = 0; kp < NPH; ++kp) {
        __syncthreads();
        // ---- stage: 1536 float4 loads, 6/thread; each covers 4 rows ----
#pragma unroll
        for (int l = 0; l < 6; ++l) {
            int gid = l * 256 + tid;
            float* Sb;
            int h, w0, c, e, row0;
            if (gid < 512) {               // Si (64 rows): kl(1)|r(4)|m4(4)
                int q = gid;
                int kl = q & 1;
                int r = (q >> 1) & 15;
                int m4 = q >> 5;
                int k = kp * KC + kl;
                h = m4 * 64 + (r >> 2) * 16 + (I >> 2);
                w0 = (r & 3) * 256 + k * 16 + 4 * (I & 3);
                c = (kl << 2) | (r >> 2);
                e = r & 3;
                row0 = m4;                 // row(dd) = m4 + 16*dd
                Sb = (float*)Si;
            } else {                       // Sj (128 rows): g(1)|kl(1)|r(4)|m4(4)
                int q = gid - 512;
                int g = q & 1;
                int kl = (q >> 1) & 1;
                int r = (q >> 2) & 15;
                int m4 = q >> 6;
                int k = kp * KC + kl;
                h = m4 * 64 + (r >> 2) * 16 + (J >> 1);
                w0 = (r & 3) * 256 + k * 16 + 8 * (J & 1) + 4 * g;
                c = (kl << 2) | (r >> 2);
                e = r & 3;
                row0 = g * 64 + m4;        // row(dd) = row0 + 16*dd
                Sb = (float*)Sj;
            }
            float4 v = *(const float4*)&x[h * 1024 + w0];
#pragma unroll
            for (int dd = 0; dd < 4; ++dd) {
                float val = (dd == 0) ? v.x : (dd == 1) ? v.y : (dd == 2) ? v.z : v.w;
                int row = row0 + dd * 16;
                int ch = c ^ swzrow(row);
                Sb[(row * RSTRIDE + ch) * 4 + e] = val;
            }
        }
        __syncthreads();
        // ---- per-column sq: plain adds, r ascending; 384 values ----
#pragma unroll
        for (int s = 0; s < 2; ++s) {
            int idx = s * 256 + tid;
            if (idx < 384) {
                const float4* Sb;
                float* out;
                int row, kl;
                if (idx < 128) {
                    kl = idx >> 6;
                    row = idx & 63;
                    Sb = Si + row * RSTRIDE;
                    out = &sqi[kl][row];
                } else {
                    int e2 = idx - 128;
                    kl = e2 >> 7;
                    row = e2 & 127;
                    Sb = Sj + row * RSTRIDE;
                    out = &sqj[kl][row];
                }
                int swz = swzrow(row);
                float acc;
                {
                    float4 v = Sb[(kl * 4) ^ swz];
                    acc = v.x * v.x;
                    float t1 = v.y * v.y; acc = acc + t1;
                    float t2 = v.z * v.z; acc = acc + t2;
                    float t3 = v.w * v.w; acc = acc + t3;
                }
#pragma unroll
                for (int rc = 1; rc < 4; ++rc) {
                    float4 v = Sb[(kl * 4 + rc) ^ swz];
                    float t0 = v.x * v.x; acc = acc + t0;
                    float t1 = v.y * v.y; acc = acc + t1;
                    float t2 = v.z * v.z; acc = acc + t2;
                    float t3 = v.w * v.w; acc = acc + t3;
                }
                *out = acc;
            }
        }
        __syncthreads();
        // ---- compute: 4x8 cells via named float4 accumulators ----
        if (active) {
#pragma unroll
            for (int kl = 0; kl < KC; ++kl) {
                float4 d0A = {0.f, 0.f, 0.f, 0.f}, d0B = {0.f, 0.f, 0.f, 0.f};
                float4 d1A = {0.f, 0.f, 0.f, 0.f}, d1B = {0.f, 0.f, 0.f, 0.f};
                float4 d2A = {0.f, 0.f, 0.f, 0.f}, d2B = {0.f, 0.f, 0.f, 0.f};
                float4 d3A = {0.f, 0.f, 0.f, 0.f}, d3B = {0.f, 0.f, 0.f, 0.f};
#pragma unroll
                for (int rc = 0; rc < 4; ++rc) {
                    const int c = kl * 4 + rc;
                    LDA(0) LDA(1) LDA(2) LDA(3)
                    COL(0, A.x)
                    COL(1, A.y)
                    COL(2, A.z)
                    COL(3, A.w)
                    COL(4, B.x)
                    COL(5, B.y)
                    COL(6, B.z)
                    COL(7, B.w)
                }
                const float4 si4 = *(const float4*)&sqi[kl][ty * 4];
                const float4 sj0 = *(const float4*)&sqj[kl][tx * 8];
                const float4 sj1 = *(const float4*)&sqj[kl][tx * 8 + 4];
                EPIROW(0, si4.x)
                EPIROW(1, si4.y)
                EPIROW(2, si4.z)
                EPIROW(3, si4.w)
            }
        }
    }

    // ---- stores: direct + mirrored (all under active) ----
    if (active) {
#pragma unroll
        for (int u = 0; u < 4; ++u) {
            unsigned m8 = (fail >> (u * 8)) & 0xffu;
            float4 o0, o1;
            o0.x = (m8 & 1u)   ? 0.0f : 1.0f;
            o0.y = (m8 & 2u)   ? 0.0f : 1.0f;
            o0.z = (m8 & 4u)   ? 0.0f : 1.0f;
            o0.w = (m8 & 8u)   ? 0.0f : 1.0f;
            o1.x = (m8 & 16u)  ? 0.0f : 1.0f;
            o1.y = (m8 & 32u)  ? 0.0f : 1.0f;
            o1.z = (m8 & 64u)  ? 0.0f : 1.0f;
            o1.w = (m8 & 128u) ? 0.0f : 1.0f;
            size_t base = (size_t)(i0 + ty * 4 + u) * NPATCH + j0 + tx * 8;
            *(float4*)&A[base] = o0;
            *(float4*)&A[base + 4] = o1;
        }
#pragma unroll
        for (int v = 0; v < 8; ++v) {
            float4 o;
            o.x = ((fail >> (0 * 8 + v)) & 1u) ? 0.0f : 1.0f;
            o.y = ((fail >> (1 * 8 + v)) & 1u) ? 0.0f : 1.0f;
            o.z = ((fail >> (2 * 8 + v)) & 1u) ? 0.0f : 1.0f;
            o.w = ((fail >> (3 * 8 + v)) & 1u) ? 0.0f : 1.0f;
            *(float4*)&A[(size_t)(j0 + tx * 8 + v) * NPATCH + i0 + ty * 4] = o;
        }
    }
}

extern "C" void kernel_launch(void* const* d_in, const int* in_sizes, int n_in,
                              void* d_out, int out_size, void* d_ws, size_t ws_size,
                              hipStream_t stream) {
    const float* x = (const float*)d_in[0];
    float* A = (float*)d_out;
    (void)d_ws; (void)ws_size;

    const int nblk = 1056;  // tiles I>=2J: sum_J (64-2J)
    adj_kernel<<<nblk, 256, 0, stream>>>(x, A);
}